// Round 1
// baseline (345.581 us; speedup 1.0000x reference)
//
#include <hip/hip_runtime.h>

// x: (65536, 1024) float32, values in {0,1}. OR-tree == per-row any(x >= 0.5).
// One wave (64 lanes) per row: each lane reads 4 x float4 (16 floats),
// coalesced; wave-wide __any(); lane 0 writes 1.0f/0.0f.

#define THRESH 0.5f
#define ROW_LEN 1024
#define ROWS_PER_BLOCK 4  // 256 threads = 4 waves

__global__ __launch_bounds__(256) void or_tree_kernel(const float* __restrict__ x,
                                                      float* __restrict__ out) {
    const int wave = threadIdx.x >> 6;       // 0..3 within block
    const int lane = threadIdx.x & 63;       // wave64
    const long long row = (long long)blockIdx.x * ROWS_PER_BLOCK + wave;

    const float4* rp = (const float4*)(x + row * (long long)ROW_LEN);

    bool local_any = false;
#pragma unroll
    for (int k = 0; k < 4; ++k) {
        float4 v = rp[lane + k * 64];  // lanes stride 16B -> 1KiB coalesced segment
        local_any = local_any | (v.x >= THRESH) | (v.y >= THRESH) |
                    (v.z >= THRESH) | (v.w >= THRESH);
    }

    if (__any(local_any ? 1 : 0)) {
        if (lane == 0) out[row] = 1.0f;
    } else {
        if (lane == 0) out[row] = 0.0f;
    }
}

extern "C" void kernel_launch(void* const* d_in, const int* in_sizes, int n_in,
                              void* d_out, int out_size, void* d_ws, size_t ws_size,
                              hipStream_t stream) {
    const float* x = (const float*)d_in[0];
    float* out = (float*)d_out;
    const int n_rows = out_size;                       // 65536
    const int grid = n_rows / ROWS_PER_BLOCK;          // 16384 blocks
    or_tree_kernel<<<grid, 256, 0, stream>>>(x, out);
}

// Round 2
// 303.633 us; speedup vs baseline: 1.1382x; 1.1382x over previous
//
#include <hip/hip_runtime.h>

// x: (65536, 1024) float32, values in {0,1}. OR-tree == per-row any(x >= 0.5).
// One wave (64 lanes) per row. Short-circuit scan: each loop iteration the
// wave reads a contiguous 1 KiB chunk (lane i -> float4 at 16B*i); if any
// lane saw a nonzero, the whole wave stops (uniform branch via __any).
// Worst case (all-zero row) reads the full 4 KiB row -> always correct.

#define THRESH 0.5f
#define ROW_LEN 1024
#define ROWS_PER_BLOCK 4  // 256 threads = 4 waves

__global__ __launch_bounds__(256) void or_tree_kernel(const float* __restrict__ x,
                                                      float* __restrict__ out) {
    const int wave = threadIdx.x >> 6;       // 0..3 within block
    const int lane = threadIdx.x & 63;       // wave64
    const long long row = (long long)blockIdx.x * ROWS_PER_BLOCK + wave;

    const float4* rp = (const float4*)(x + row * (long long)ROW_LEN);

    bool found = false;
#pragma unroll 1
    for (int k = 0; k < 4; ++k) {
        float4 v = rp[lane + k * 64];  // 64 lanes x 16B = coalesced 1KiB chunk
        bool local_any = (v.x >= THRESH) | (v.y >= THRESH) |
                         (v.z >= THRESH) | (v.w >= THRESH);
        if (__any(local_any ? 1 : 0)) {  // wave-uniform -> no divergence
            found = true;
            break;                        // short-circuit: skip remaining chunks
        }
    }

    if (lane == 0) out[row] = found ? 1.0f : 0.0f;
}

extern "C" void kernel_launch(void* const* d_in, const int* in_sizes, int n_in,
                              void* d_out, int out_size, void* d_ws, size_t ws_size,
                              hipStream_t stream) {
    const float* x = (const float*)d_in[0];
    float* out = (float*)d_out;
    const int n_rows = out_size;                       // 65536
    const int grid = n_rows / ROWS_PER_BLOCK;          // 16384 blocks
    or_tree_kernel<<<grid, 256, 0, stream>>>(x, out);
}

// Round 3
// 296.301 us; speedup vs baseline: 1.1663x; 1.0247x over previous
//
#include <hip/hip_runtime.h>

// x: (65536, 1024) float32, values in {0,1}. OR-tree == per-row any(x >= 0.5).
// Wave-per-row with a 64-float probe: lane i reads x[row, i] (coalesced 256 B
// per row). If any lane sees >= 0.5 (probability 1 - 2^-64 per row for this
// input distribution), done. Otherwise fall back to a full-row float4 scan —
// always correct for adversarial inputs, essentially never taken here.

#define THRESH 0.5f
#define ROW_LEN 1024
#define ROWS_PER_BLOCK 4  // 256 threads = 4 waves

__global__ __launch_bounds__(256) void or_tree_kernel(const float* __restrict__ x,
                                                      float* __restrict__ out) {
    const int wave = threadIdx.x >> 6;       // 0..3 within block
    const int lane = threadIdx.x & 63;       // wave64
    const long long row = (long long)blockIdx.x * ROWS_PER_BLOCK + wave;

    const float* rp = x + row * (long long)ROW_LEN;

    // Probe: first 64 floats, one per lane (coalesced 256 B).
    bool found = (rp[lane] >= THRESH);

    if (!__any(found ? 1 : 0)) {
        // Fallback (P ~= 2^-64 per row on this input): scan the full row.
        const float4* rp4 = (const float4*)rp;
        found = false;
#pragma unroll 1
        for (int k = 0; k < 4; ++k) {
            float4 v = rp4[lane + k * 64];
            bool local_any = (v.x >= THRESH) | (v.y >= THRESH) |
                             (v.z >= THRESH) | (v.w >= THRESH);
            if (__any(local_any ? 1 : 0)) { found = true; break; }
        }
    } else {
        found = true;
    }

    if (lane == 0) out[row] = found ? 1.0f : 0.0f;
}

extern "C" void kernel_launch(void* const* d_in, const int* in_sizes, int n_in,
                              void* d_out, int out_size, void* d_ws, size_t ws_size,
                              hipStream_t stream) {
    const float* x = (const float*)d_in[0];
    float* out = (float*)d_out;
    const int n_rows = out_size;                       // 65536
    const int grid = n_rows / ROWS_PER_BLOCK;          // 16384 blocks
    or_tree_kernel<<<grid, 256, 0, stream>>>(x, out);
}